// Round 8
// baseline (243.481 us; speedup 1.0000x reference)
//
#include <hip/hip_runtime.h>
#include <hip/hip_bf16.h>

#define N_ROWS 8192
#define D_DIM  512
#define NSTEPS 8    // K-steps of BK=64

typedef __attribute__((ext_vector_type(4))) int   i32x4;
typedef __attribute__((ext_vector_type(8))) int   i32x8;
typedef __attribute__((ext_vector_type(16))) float f32x16;

typedef const __attribute__((address_space(1))) void* gptr_t;
typedef __attribute__((address_space(3))) void* lptr_t;

static __device__ __forceinline__ void gload16(const void* g, void* l) {
    __builtin_amdgcn_global_load_lds((gptr_t)g, (lptr_t)l, 16, 0, 0);
}
#define VMCNT(n)  asm volatile("s_waitcnt vmcnt(" #n ")" ::: "memory")
#define BARRIER() __builtin_amdgcn_s_barrier()
#define SCHED0()  __builtin_amdgcn_sched_barrier(0)

// One wave per row-index i: L2-normalize cxr_i and ehr_i, write fp8 e4m3,
// and compute diag_i = dot(cxr_i,ehr_i)*ia*ib/temp (full fp32) in one pass.
__global__ void normdiag_kernel(const float* __restrict__ cxr, const float* __restrict__ ehr,
                                unsigned char* __restrict__ Ab, unsigned char* __restrict__ Bb,
                                const float* __restrict__ temp, float* __restrict__ dg) {
    const int row = blockIdx.x * 4 + (threadIdx.x >> 6);
    const int lane = threadIdx.x & 63;
    const float4* a4 = (const float4*)(cxr + (size_t)row * D_DIM + lane * 8);
    const float4* b4 = (const float4*)(ehr + (size_t)row * D_DIM + lane * 8);
    float4 a0 = a4[0], a1 = a4[1];
    float4 b0 = b4[0], b1 = b4[1];
    float sa = a0.x*a0.x + a0.y*a0.y + a0.z*a0.z + a0.w*a0.w
             + a1.x*a1.x + a1.y*a1.y + a1.z*a1.z + a1.w*a1.w;
    float sb = b0.x*b0.x + b0.y*b0.y + b0.z*b0.z + b0.w*b0.w
             + b1.x*b1.x + b1.y*b1.y + b1.z*b1.z + b1.w*b1.w;
    float dt = a0.x*b0.x + a0.y*b0.y + a0.z*b0.z + a0.w*b0.w
             + a1.x*b1.x + a1.y*b1.y + a1.z*b1.z + a1.w*b1.w;
#pragma unroll
    for (int s = 1; s < 64; s <<= 1) {
        sa += __shfl_xor(sa, s);
        sb += __shfl_xor(sb, s);
        dt += __shfl_xor(dt, s);
    }
    const float ia = 1.0f / sqrtf(fmaxf(sa, 1e-16f));
    const float ib = 1.0f / sqrtf(fmaxf(sb, 1e-16f));
    if (lane == 0) dg[row] = dt * ia * ib / temp[0];
    float va[8] = {a0.x, a0.y, a0.z, a0.w, a1.x, a1.y, a1.z, a1.w};
    float vb[8] = {b0.x, b0.y, b0.z, b0.w, b1.x, b1.y, b1.z, b1.w};
    int aw0 = __builtin_amdgcn_cvt_pk_fp8_f32(va[0]*ia, va[1]*ia, 0, false);
    aw0     = __builtin_amdgcn_cvt_pk_fp8_f32(va[2]*ia, va[3]*ia, aw0, true);
    int aw1 = __builtin_amdgcn_cvt_pk_fp8_f32(va[4]*ia, va[5]*ia, 0, false);
    aw1     = __builtin_amdgcn_cvt_pk_fp8_f32(va[6]*ia, va[7]*ia, aw1, true);
    int bw0 = __builtin_amdgcn_cvt_pk_fp8_f32(vb[0]*ib, vb[1]*ib, 0, false);
    bw0     = __builtin_amdgcn_cvt_pk_fp8_f32(vb[2]*ib, vb[3]*ib, bw0, true);
    int bw1 = __builtin_amdgcn_cvt_pk_fp8_f32(vb[4]*ib, vb[5]*ib, 0, false);
    bw1     = __builtin_amdgcn_cvt_pk_fp8_f32(vb[6]*ib, vb[7]*ib, bw1, true);
    *(int2*)(Ab + (size_t)row * D_DIM + lane * 8) = make_int2(aw0, aw1);
    *(int2*)(Bb + (size_t)row * D_DIM + lane * 8) = make_int2(bw0, bw1);
}

// fp8 128x256 GEMM, mfma_scale_f32_32x32x64 (scale=1.0), BK=64, 8 waves (2x4),
// wave tile 64x64 -> acc = 64 VGPR; <=128 regs/wave so 2 blocks/CU co-reside
// (cross-block DS||MFMA overlap). 3-deep LDS ring (75 KB), counted VMCNT(3).
// Epilogue: exp((cos-1)/T), diag zeroed, row/col sums -> global atomics.
__global__ __launch_bounds__(512, 4) void gemm_lse_kernel(
        const unsigned char* __restrict__ A, const unsigned char* __restrict__ B,
        const float* __restrict__ temp,
        float* __restrict__ row_sum, float* __restrict__ col_sum) {
    __shared__ unsigned char As[3][8192];    // 3 x [128 rows][64 k] fp8 = 24 KB
    __shared__ unsigned char Bs[3][16384];   // 3 x [256 rows][64 k] fp8 = 48 KB
    __shared__ float rs_l[128];
    __shared__ float cs_l[256];

    const int tid = threadIdx.x;
    const int lane = tid & 63;
    const int wid = tid >> 6;
    const int bm = blockIdx.x, bn = blockIdx.y;   // 64 x 32
    const int wm = wid >> 2, wn = wid & 3;        // wave tile 64x64

    if (tid < 128) rs_l[tid] = 0.f;
    if (tid >= 128 && tid < 384) cs_l[tid - 128] = 0.f;

    // staging: lane l -> LDS row base+(l>>2), 16B-slot l&3 (linear = base+l*16).
    // Source slot = (l&3)^((row>>1)&3) = (l&3)^((l>>3)&3)  [T2 involution]
    const int swz = ((lane & 3) ^ ((lane >> 3) & 3)) * 16;
    const unsigned char* gA = A + (size_t)(bm * 128 + wid * 16 + (lane >> 2)) * D_DIM + swz;
    const unsigned char* gB = B + (size_t)(bn * 256 + wid * 16 + (lane >> 2)) * D_DIM + swz;

#define STG_A(d, st) gload16(gA + (st) * 64, &As[d][(wid * 16) * 64])
#define STG_B(d, h, st) gload16(gB + (size_t)((h) * 128) * D_DIM + (st) * 64, \
                                &Bs[d][((h) * 128 + wid * 16) * 64])

    // fragment reads: lane covers row base+c31, k-half h2 (32 B = 2 b128).
    // LDS slot of global slot s_g at row r: s_g ^ ((r>>1)&3), (r>>1)&3=(c31>>1)&3.
    const int c31 = lane & 31, h2 = lane >> 5;
    const int xr = (c31 >> 1) & 3;
    const int so0 = ((2 * h2) ^ xr) * 16;
    const int so1 = ((2 * h2 + 1) ^ xr) * 16;

    f32x16 acc[2][2] = {};
    const int sc = 0x7F7F7F7F;   // E8M0 127 -> scale 1.0 for any opsel

    // prologue: stage steps 0,1 (3 gloads each); drain step 0, keep 1 flying
    STG_A(0, 0); STG_B(0, 0, 0); STG_B(0, 1, 0);
    STG_A(1, 1); STG_B(1, 0, 1); STG_B(1, 1, 1);
    VMCNT(3);
    BARRIER(); SCHED0();

#pragma unroll
    for (int s = 0; s < NSTEPS; ++s) {
        const int d = s % 3;
        if (s + 2 < NSTEPS) {
            const int dn = (s + 2) % 3;
            STG_A(dn, s + 2); STG_B(dn, 0, s + 2); STG_B(dn, 1, s + 2);
        }
        i32x8 Af[2], Bf[2];
#pragma unroll
        for (int mi = 0; mi < 2; ++mi) {
            const int r = wm * 64 + mi * 32 + c31;
            i32x4 lo = *(const i32x4*)&As[d][r * 64 + so0];
            i32x4 hi = *(const i32x4*)&As[d][r * 64 + so1];
            Af[mi] = (i32x8){lo[0], lo[1], lo[2], lo[3], hi[0], hi[1], hi[2], hi[3]};
        }
#pragma unroll
        for (int ni = 0; ni < 2; ++ni) {
            const int r = wn * 64 + ni * 32 + c31;
            i32x4 lo = *(const i32x4*)&Bs[d][r * 64 + so0];
            i32x4 hi = *(const i32x4*)&Bs[d][r * 64 + so1];
            Bf[ni] = (i32x8){lo[0], lo[1], lo[2], lo[3], hi[0], hi[1], hi[2], hi[3]};
        }
#pragma unroll
        for (int mi = 0; mi < 2; ++mi)
#pragma unroll
            for (int ni = 0; ni < 2; ++ni)
                acc[mi][ni] = __builtin_amdgcn_mfma_scale_f32_32x32x64_f8f6f4(
                    Af[mi], Bf[ni], acc[mi][ni], 0, 0, 0, sc, 0, sc);

        // boundary: certify step s+1 landed for all waves; keep s+2 flying
        if (s <= NSTEPS - 3)       { VMCNT(3); BARRIER(); SCHED0(); }
        else if (s == NSTEPS - 2)  { VMCNT(0); BARRIER(); SCHED0(); }
    }

    // ---- epilogue: exp + masked diag + row/col reduction ----
    // C/D 32x32 layout: col = lane&31, row = (reg&3) + 8*(reg>>2) + 4*(lane>>5)
    const float invT = 1.0f / temp[0];
    const bool diagBlk = ((bm >> 1) == bn);
    float colpart[2] = {0.f, 0.f};

#pragma unroll
    for (int mi = 0; mi < 2; ++mi) {
        float rowpart[16];
#pragma unroll
        for (int r = 0; r < 16; ++r) rowpart[r] = 0.f;
#pragma unroll
        for (int ni = 0; ni < 2; ++ni) {
            f32x16 a = acc[mi][ni];
#pragma unroll
            for (int r = 0; r < 16; ++r) {
                float e = __expf((a[r] - 1.0f) * invT);
                if (diagBlk) {
                    int grow = bm * 128 + wm * 64 + mi * 32 + (r & 3) + 8 * (r >> 2) + 4 * h2;
                    int gcol = bn * 256 + wn * 64 + ni * 32 + c31;
                    if (grow == gcol) e = 0.f;
                }
                rowpart[r] += e;
                colpart[ni] += e;
            }
        }
#pragma unroll
        for (int r = 0; r < 16; ++r) {
            float v = rowpart[r];
            v += __shfl_xor(v, 1);
            v += __shfl_xor(v, 2);
            v += __shfl_xor(v, 4);
            v += __shfl_xor(v, 8);
            v += __shfl_xor(v, 16);
            if (c31 == 0)
                atomicAdd(&rs_l[wm * 64 + mi * 32 + (r & 3) + 8 * (r >> 2) + 4 * h2], v);
        }
    }
#pragma unroll
    for (int ni = 0; ni < 2; ++ni) {
        float v = colpart[ni];
        v += __shfl_xor(v, 32);
        if (h2 == 0) atomicAdd(&cs_l[wn * 64 + ni * 32 + c31], v);
    }
    __syncthreads();
    if (tid < 128) atomicAdd(&row_sum[bm * 128 + tid], rs_l[tid]);
    else if (tid < 384) atomicAdd(&col_sum[bn * 256 + (tid - 128)], cs_l[tid - 128]);
}

// loss = mean_i [ 2M + log(rs_i) + log(cs_i) - 2*diag_i ],  M = 1/temp
__global__ void finalize_kernel(const float* __restrict__ rs, const float* __restrict__ cs,
                                const float* __restrict__ dg, const float* __restrict__ temp,
                                float* __restrict__ out) {
    const float M = 1.0f / temp[0];
    float acc = 0.f;
    for (int i = threadIdx.x; i < N_ROWS; i += 256)
        acc += 2.f * M + __logf(rs[i]) + __logf(cs[i]) - 2.f * dg[i];
#pragma unroll
    for (int s = 1; s < 64; s <<= 1) acc += __shfl_xor(acc, s);
    __shared__ float wsum[4];
    if ((threadIdx.x & 63) == 0) wsum[threadIdx.x >> 6] = acc;
    __syncthreads();
    if (threadIdx.x == 0)
        out[0] = (wsum[0] + wsum[1] + wsum[2] + wsum[3]) / (float)N_ROWS;
}

extern "C" void kernel_launch(void* const* d_in, const int* in_sizes, int n_in,
                              void* d_out, int out_size, void* d_ws, size_t ws_size,
                              hipStream_t stream) {
    const float* cxr = (const float*)d_in[0];
    const float* ehr = (const float*)d_in[1];
    const float* temp = (const float*)d_in[2];
    float* out = (float*)d_out;

    char* ws = (char*)d_ws;
    unsigned char* Ab = (unsigned char*)ws;                        // 4 MB
    unsigned char* Bb = (unsigned char*)(ws + 4u * 1024 * 1024);   // 4 MB
    float* rs = (float*)(ws + 8u * 1024 * 1024);
    float* cs = rs + N_ROWS;
    float* dg = cs + N_ROWS;

    hipMemsetAsync(rs, 0, 2 * N_ROWS * sizeof(float), stream);
    normdiag_kernel<<<dim3(N_ROWS / 4), 256, 0, stream>>>(cxr, ehr, Ab, Bb, temp, dg);
    gemm_lse_kernel<<<dim3(64, 32), 512, 0, stream>>>(Ab, Bb, temp, rs, cs);
    finalize_kernel<<<1, 256, 0, stream>>>(rs, cs, dg, temp, out);
}

// Round 9
// 127.899 us; speedup vs baseline: 1.9037x; 1.9037x over previous
//
#include <hip/hip_runtime.h>
#include <hip/hip_bf16.h>

#define N_ROWS 8192
#define D_DIM  512
#define NSTEPS 8    // K-steps of BK=64

typedef __attribute__((ext_vector_type(4))) int   i32x4;
typedef __attribute__((ext_vector_type(8))) int   i32x8;
typedef __attribute__((ext_vector_type(16))) float f32x16;

typedef const __attribute__((address_space(1))) void* gptr_t;
typedef __attribute__((address_space(3))) void* lptr_t;

static __device__ __forceinline__ void gload16(const void* g, void* l) {
    __builtin_amdgcn_global_load_lds((gptr_t)g, (lptr_t)l, 16, 0, 0);
}
#define VMCNT(n)  asm volatile("s_waitcnt vmcnt(" #n ")" ::: "memory")
#define BARRIER() __builtin_amdgcn_s_barrier()
#define SCHED0()  __builtin_amdgcn_sched_barrier(0)

// One wave per row-index i: L2-normalize cxr_i and ehr_i, write fp8 e4m3,
// and compute diag_i = dot(cxr_i,ehr_i)*ia*ib/temp (full fp32) in one pass.
__global__ void normdiag_kernel(const float* __restrict__ cxr, const float* __restrict__ ehr,
                                unsigned char* __restrict__ Ab, unsigned char* __restrict__ Bb,
                                const float* __restrict__ temp, float* __restrict__ dg) {
    const int row = blockIdx.x * 4 + (threadIdx.x >> 6);
    const int lane = threadIdx.x & 63;
    const float4* a4 = (const float4*)(cxr + (size_t)row * D_DIM + lane * 8);
    const float4* b4 = (const float4*)(ehr + (size_t)row * D_DIM + lane * 8);
    float4 a0 = a4[0], a1 = a4[1];
    float4 b0 = b4[0], b1 = b4[1];
    float sa = a0.x*a0.x + a0.y*a0.y + a0.z*a0.z + a0.w*a0.w
             + a1.x*a1.x + a1.y*a1.y + a1.z*a1.z + a1.w*a1.w;
    float sb = b0.x*b0.x + b0.y*b0.y + b0.z*b0.z + b0.w*b0.w
             + b1.x*b1.x + b1.y*b1.y + b1.z*b1.z + b1.w*b1.w;
    float dt = a0.x*b0.x + a0.y*b0.y + a0.z*b0.z + a0.w*b0.w
             + a1.x*b1.x + a1.y*b1.y + a1.z*b1.z + a1.w*b1.w;
#pragma unroll
    for (int s = 1; s < 64; s <<= 1) {
        sa += __shfl_xor(sa, s);
        sb += __shfl_xor(sb, s);
        dt += __shfl_xor(dt, s);
    }
    const float ia = 1.0f / sqrtf(fmaxf(sa, 1e-16f));
    const float ib = 1.0f / sqrtf(fmaxf(sb, 1e-16f));
    if (lane == 0) dg[row] = dt * ia * ib / temp[0];
    float va[8] = {a0.x, a0.y, a0.z, a0.w, a1.x, a1.y, a1.z, a1.w};
    float vb[8] = {b0.x, b0.y, b0.z, b0.w, b1.x, b1.y, b1.z, b1.w};
    int aw0 = __builtin_amdgcn_cvt_pk_fp8_f32(va[0]*ia, va[1]*ia, 0, false);
    aw0     = __builtin_amdgcn_cvt_pk_fp8_f32(va[2]*ia, va[3]*ia, aw0, true);
    int aw1 = __builtin_amdgcn_cvt_pk_fp8_f32(va[4]*ia, va[5]*ia, 0, false);
    aw1     = __builtin_amdgcn_cvt_pk_fp8_f32(va[6]*ia, va[7]*ia, aw1, true);
    int bw0 = __builtin_amdgcn_cvt_pk_fp8_f32(vb[0]*ib, vb[1]*ib, 0, false);
    bw0     = __builtin_amdgcn_cvt_pk_fp8_f32(vb[2]*ib, vb[3]*ib, bw0, true);
    int bw1 = __builtin_amdgcn_cvt_pk_fp8_f32(vb[4]*ib, vb[5]*ib, 0, false);
    bw1     = __builtin_amdgcn_cvt_pk_fp8_f32(vb[6]*ib, vb[7]*ib, bw1, true);
    *(int2*)(Ab + (size_t)row * D_DIM + lane * 8) = make_int2(aw0, aw1);
    *(int2*)(Bb + (size_t)row * D_DIM + lane * 8) = make_int2(bw0, bw1);
}

// fp8 128x256 GEMM, mfma_scale_f32_32x32x64 (scale=1.0), BK=64, 8 waves (2x4),
// wave tile 64x64 -> acc = 64 VGPR. __launch_bounds__(512,2): empirically this
// hipcc caps VGPR at 2048/(arg*waves_per_block) -> (512,2)=128-reg cap, which
// fits the ~116-reg demand (r8's (512,4)=64-reg cap caused 625 MB spill).
// 2 blocks/CU (150 KB LDS) -> cross-block DS||MFMA overlap. 3-deep ring, VMCNT(3).
__global__ __launch_bounds__(512, 2) void gemm_lse_kernel(
        const unsigned char* __restrict__ A, const unsigned char* __restrict__ B,
        const float* __restrict__ temp,
        float* __restrict__ row_sum, float* __restrict__ col_sum) {
    __shared__ unsigned char As[3][8192];    // 3 x [128 rows][64 k] fp8 = 24 KB
    __shared__ unsigned char Bs[3][16384];   // 3 x [256 rows][64 k] fp8 = 48 KB
    __shared__ float rs_l[128];
    __shared__ float cs_l[256];

    const int tid = threadIdx.x;
    const int lane = tid & 63;
    const int wid = tid >> 6;
    const int bm = blockIdx.x, bn = blockIdx.y;   // 64 x 32
    const int wm = wid >> 2, wn = wid & 3;        // wave tile 64x64

    if (tid < 128) rs_l[tid] = 0.f;
    if (tid >= 128 && tid < 384) cs_l[tid - 128] = 0.f;

    // staging: lane l -> LDS row base+(l>>2), 16B-slot l&3 (linear = base+l*16).
    // Source slot = (l&3)^((row>>1)&3) = (l&3)^((l>>3)&3)  [T2 involution]
    const int swz = ((lane & 3) ^ ((lane >> 3) & 3)) * 16;
    const unsigned char* gA = A + (size_t)(bm * 128 + wid * 16 + (lane >> 2)) * D_DIM + swz;
    const unsigned char* gB = B + (size_t)(bn * 256 + wid * 16 + (lane >> 2)) * D_DIM + swz;

#define STG_A(d, st) gload16(gA + (st) * 64, &As[d][(wid * 16) * 64])
#define STG_B(d, h, st) gload16(gB + (size_t)((h) * 128) * D_DIM + (st) * 64, \
                                &Bs[d][((h) * 128 + wid * 16) * 64])

    // fragment reads: lane covers row base+c31, k-half h2 (32 B = 2 b128).
    // LDS slot of global slot s_g at row r: s_g ^ ((r>>1)&3), (r>>1)&3=(c31>>1)&3.
    const int c31 = lane & 31, h2 = lane >> 5;
    const int xr = (c31 >> 1) & 3;
    const int so0 = ((2 * h2) ^ xr) * 16;
    const int so1 = ((2 * h2 + 1) ^ xr) * 16;

    f32x16 acc[2][2] = {};
    const int sc = 0x7F7F7F7F;   // E8M0 127 -> scale 1.0 for any opsel

    // prologue: stage steps 0,1 (3 gloads each); drain step 0, keep 1 flying
    STG_A(0, 0); STG_B(0, 0, 0); STG_B(0, 1, 0);
    STG_A(1, 1); STG_B(1, 0, 1); STG_B(1, 1, 1);
    VMCNT(3);
    BARRIER(); SCHED0();

#pragma unroll
    for (int s = 0; s < NSTEPS; ++s) {
        const int d = s % 3;
        if (s + 2 < NSTEPS) {
            const int dn = (s + 2) % 3;
            STG_A(dn, s + 2); STG_B(dn, 0, s + 2); STG_B(dn, 1, s + 2);
        }
        i32x8 Af[2], Bf[2];
#pragma unroll
        for (int mi = 0; mi < 2; ++mi) {
            const int r = wm * 64 + mi * 32 + c31;
            i32x4 lo = *(const i32x4*)&As[d][r * 64 + so0];
            i32x4 hi = *(const i32x4*)&As[d][r * 64 + so1];
            Af[mi] = (i32x8){lo[0], lo[1], lo[2], lo[3], hi[0], hi[1], hi[2], hi[3]};
        }
#pragma unroll
        for (int ni = 0; ni < 2; ++ni) {
            const int r = wn * 64 + ni * 32 + c31;
            i32x4 lo = *(const i32x4*)&Bs[d][r * 64 + so0];
            i32x4 hi = *(const i32x4*)&Bs[d][r * 64 + so1];
            Bf[ni] = (i32x8){lo[0], lo[1], lo[2], lo[3], hi[0], hi[1], hi[2], hi[3]};
        }
#pragma unroll
        for (int mi = 0; mi < 2; ++mi)
#pragma unroll
            for (int ni = 0; ni < 2; ++ni)
                acc[mi][ni] = __builtin_amdgcn_mfma_scale_f32_32x32x64_f8f6f4(
                    Af[mi], Bf[ni], acc[mi][ni], 0, 0, 0, sc, 0, sc);

        // boundary: certify step s+1 landed for all waves; keep s+2 flying
        if (s <= NSTEPS - 3)       { VMCNT(3); BARRIER(); SCHED0(); }
        else if (s == NSTEPS - 2)  { VMCNT(0); BARRIER(); SCHED0(); }
    }

    // ---- epilogue: exp + masked diag + row/col reduction ----
    // C/D 32x32 layout: col = lane&31, row = (reg&3) + 8*(reg>>2) + 4*(lane>>5)
    const float invT = 1.0f / temp[0];
    const bool diagBlk = ((bm >> 1) == bn);
    float colpart[2] = {0.f, 0.f};

#pragma unroll
    for (int mi = 0; mi < 2; ++mi) {
        float rowpart[16];
#pragma unroll
        for (int r = 0; r < 16; ++r) rowpart[r] = 0.f;
#pragma unroll
        for (int ni = 0; ni < 2; ++ni) {
            f32x16 a = acc[mi][ni];
#pragma unroll
            for (int r = 0; r < 16; ++r) {
                float e = __expf((a[r] - 1.0f) * invT);
                if (diagBlk) {
                    int grow = bm * 128 + wm * 64 + mi * 32 + (r & 3) + 8 * (r >> 2) + 4 * h2;
                    int gcol = bn * 256 + wn * 64 + ni * 32 + c31;
                    if (grow == gcol) e = 0.f;
                }
                rowpart[r] += e;
                colpart[ni] += e;
            }
        }
#pragma unroll
        for (int r = 0; r < 16; ++r) {
            float v = rowpart[r];
            v += __shfl_xor(v, 1);
            v += __shfl_xor(v, 2);
            v += __shfl_xor(v, 4);
            v += __shfl_xor(v, 8);
            v += __shfl_xor(v, 16);
            if (c31 == 0)
                atomicAdd(&rs_l[wm * 64 + mi * 32 + (r & 3) + 8 * (r >> 2) + 4 * h2], v);
        }
    }
#pragma unroll
    for (int ni = 0; ni < 2; ++ni) {
        float v = colpart[ni];
        v += __shfl_xor(v, 32);
        if (h2 == 0) atomicAdd(&cs_l[wn * 64 + ni * 32 + c31], v);
    }
    __syncthreads();
    if (tid < 128) atomicAdd(&row_sum[bm * 128 + tid], rs_l[tid]);
    else if (tid < 384) atomicAdd(&col_sum[bn * 256 + (tid - 128)], cs_l[tid - 128]);
}

// loss = mean_i [ 2M + log(rs_i) + log(cs_i) - 2*diag_i ],  M = 1/temp
__global__ void finalize_kernel(const float* __restrict__ rs, const float* __restrict__ cs,
                                const float* __restrict__ dg, const float* __restrict__ temp,
                                float* __restrict__ out) {
    const float M = 1.0f / temp[0];
    float acc = 0.f;
    for (int i = threadIdx.x; i < N_ROWS; i += 256)
        acc += 2.f * M + __logf(rs[i]) + __logf(cs[i]) - 2.f * dg[i];
#pragma unroll
    for (int s = 1; s < 64; s <<= 1) acc += __shfl_xor(acc, s);
    __shared__ float wsum[4];
    if ((threadIdx.x & 63) == 0) wsum[threadIdx.x >> 6] = acc;
    __syncthreads();
    if (threadIdx.x == 0)
        out[0] = (wsum[0] + wsum[1] + wsum[2] + wsum[3]) / (float)N_ROWS;
}

extern "C" void kernel_launch(void* const* d_in, const int* in_sizes, int n_in,
                              void* d_out, int out_size, void* d_ws, size_t ws_size,
                              hipStream_t stream) {
    const float* cxr = (const float*)d_in[0];
    const float* ehr = (const float*)d_in[1];
    const float* temp = (const float*)d_in[2];
    float* out = (float*)d_out;

    char* ws = (char*)d_ws;
    unsigned char* Ab = (unsigned char*)ws;                        // 4 MB
    unsigned char* Bb = (unsigned char*)(ws + 4u * 1024 * 1024);   // 4 MB
    float* rs = (float*)(ws + 8u * 1024 * 1024);
    float* cs = rs + N_ROWS;
    float* dg = cs + N_ROWS;

    hipMemsetAsync(rs, 0, 2 * N_ROWS * sizeof(float), stream);
    normdiag_kernel<<<dim3(N_ROWS / 4), 256, 0, stream>>>(cxr, ehr, Ab, Bb, temp, dg);
    gemm_lse_kernel<<<dim3(64, 32), 512, 0, stream>>>(Ab, Bb, temp, rs, cs);
    finalize_kernel<<<1, 256, 0, stream>>>(rs, cs, dg, temp, out);
}

// Round 10
// 125.837 us; speedup vs baseline: 1.9349x; 1.0164x over previous
//
#include <hip/hip_runtime.h>
#include <hip/hip_bf16.h>

#define N_ROWS 8192
#define D_DIM  512
#define NSTEPS 8    // K-steps of BK=64

typedef __attribute__((ext_vector_type(4))) int   i32x4;
typedef __attribute__((ext_vector_type(8))) int   i32x8;
typedef __attribute__((ext_vector_type(16))) float f32x16;

typedef const __attribute__((address_space(1))) void* gptr_t;
typedef __attribute__((address_space(3))) void* lptr_t;

static __device__ __forceinline__ void gload16(const void* g, void* l) {
    __builtin_amdgcn_global_load_lds((gptr_t)g, (lptr_t)l, 16, 0, 0);
}
#define VMCNT(n)  asm volatile("s_waitcnt vmcnt(" #n ")" ::: "memory")
#define BARRIER() __builtin_amdgcn_s_barrier()
#define SCHED0()  __builtin_amdgcn_sched_barrier(0)

// One wave per row-index i: L2-normalize cxr_i and ehr_i, write fp8 e4m3,
// and compute diag_i = dot(cxr_i,ehr_i)*ia*ib/temp (full fp32) in one pass.
__global__ void normdiag_kernel(const float* __restrict__ cxr, const float* __restrict__ ehr,
                                unsigned char* __restrict__ Ab, unsigned char* __restrict__ Bb,
                                const float* __restrict__ temp, float* __restrict__ dg) {
    const int row = blockIdx.x * 4 + (threadIdx.x >> 6);
    const int lane = threadIdx.x & 63;
    const float4* a4 = (const float4*)(cxr + (size_t)row * D_DIM + lane * 8);
    const float4* b4 = (const float4*)(ehr + (size_t)row * D_DIM + lane * 8);
    float4 a0 = a4[0], a1 = a4[1];
    float4 b0 = b4[0], b1 = b4[1];
    float sa = a0.x*a0.x + a0.y*a0.y + a0.z*a0.z + a0.w*a0.w
             + a1.x*a1.x + a1.y*a1.y + a1.z*a1.z + a1.w*a1.w;
    float sb = b0.x*b0.x + b0.y*b0.y + b0.z*b0.z + b0.w*b0.w
             + b1.x*b1.x + b1.y*b1.y + b1.z*b1.z + b1.w*b1.w;
    float dt = a0.x*b0.x + a0.y*b0.y + a0.z*b0.z + a0.w*b0.w
             + a1.x*b1.x + a1.y*b1.y + a1.z*b1.z + a1.w*b1.w;
#pragma unroll
    for (int s = 1; s < 64; s <<= 1) {
        sa += __shfl_xor(sa, s);
        sb += __shfl_xor(sb, s);
        dt += __shfl_xor(dt, s);
    }
    const float ia = 1.0f / sqrtf(fmaxf(sa, 1e-16f));
    const float ib = 1.0f / sqrtf(fmaxf(sb, 1e-16f));
    if (lane == 0) dg[row] = dt * ia * ib / temp[0];
    float va[8] = {a0.x, a0.y, a0.z, a0.w, a1.x, a1.y, a1.z, a1.w};
    float vb[8] = {b0.x, b0.y, b0.z, b0.w, b1.x, b1.y, b1.z, b1.w};
    int aw0 = __builtin_amdgcn_cvt_pk_fp8_f32(va[0]*ia, va[1]*ia, 0, false);
    aw0     = __builtin_amdgcn_cvt_pk_fp8_f32(va[2]*ia, va[3]*ia, aw0, true);
    int aw1 = __builtin_amdgcn_cvt_pk_fp8_f32(va[4]*ia, va[5]*ia, 0, false);
    aw1     = __builtin_amdgcn_cvt_pk_fp8_f32(va[6]*ia, va[7]*ia, aw1, true);
    int bw0 = __builtin_amdgcn_cvt_pk_fp8_f32(vb[0]*ib, vb[1]*ib, 0, false);
    bw0     = __builtin_amdgcn_cvt_pk_fp8_f32(vb[2]*ib, vb[3]*ib, bw0, true);
    int bw1 = __builtin_amdgcn_cvt_pk_fp8_f32(vb[4]*ib, vb[5]*ib, 0, false);
    bw1     = __builtin_amdgcn_cvt_pk_fp8_f32(vb[6]*ib, vb[7]*ib, bw1, true);
    *(int2*)(Ab + (size_t)row * D_DIM + lane * 8) = make_int2(aw0, aw1);
    *(int2*)(Bb + (size_t)row * D_DIM + lane * 8) = make_int2(bw0, bw1);
}

// fp8 64x128 GEMM, mfma_scale_f32_32x32x64 (scale=1.0), BK=64, 4 waves (2x2),
// wave tile 32x64 -> acc = 32 VGPR, ~85 total. LDS 37.6 KB -> 4 INDEPENDENT
// blocks/CU (4 separate barrier domains) to hide staging latency: when one
// block waits at its boundary, three others issue. Ring-3, counted VMCNT(3).
// Epilogue: exp((cos-1)/T), diag zeroed, row/col sums -> global atomics.
__global__ __launch_bounds__(256, 4) void gemm_lse_kernel(
        const unsigned char* __restrict__ A, const unsigned char* __restrict__ B,
        const float* __restrict__ temp,
        float* __restrict__ row_sum, float* __restrict__ col_sum) {
    __shared__ unsigned char As[3][4096];    // 3 x [64 rows][64 k] fp8 = 12 KB
    __shared__ unsigned char Bs[3][8192];    // 3 x [128 rows][64 k] fp8 = 24 KB
    __shared__ float rs_l[64];
    __shared__ float cs_l[128];

    const int tid = threadIdx.x;
    const int lane = tid & 63;
    const int wid = tid >> 6;                     // 4 waves
    const int bm = blockIdx.x & 127;              // bm-major: consecutive blocks
    const int bn = blockIdx.x >> 7;               // share the B panel (L2 hit)
    const int wm = wid >> 1, wn = wid & 1;        // wave tile 32x64

    if (tid < 64) rs_l[tid] = 0.f;
    if (tid >= 64 && tid < 192) cs_l[tid - 64] = 0.f;

    // staging: lane l -> LDS row base+(l>>2), 16B-slot l&3 (linear = base+l*16).
    // Source slot = (l&3)^((row>>1)&3) = (l&3)^((l>>3)&3)  [T2 involution]
    const int swz = ((lane & 3) ^ ((lane >> 3) & 3)) * 16;
    const unsigned char* gA = A + (size_t)(bm * 64 + wid * 16 + (lane >> 2)) * D_DIM + swz;
    const unsigned char* gB = B + (size_t)(bn * 128 + wid * 32 + (lane >> 2)) * D_DIM + swz;

#define STG_A(d, st) gload16(gA + (st) * 64, &As[d][(wid * 16) * 64])
#define STG_B(d, st) do { \
    gload16(gB + (st) * 64,                 &Bs[d][(wid * 32) * 64]); \
    gload16(gB + 16 * D_DIM + (st) * 64,    &Bs[d][(wid * 32 + 16) * 64]); } while (0)

    // fragment reads: lane covers row base+c31, k-half h2 (32 B = 2 b128).
    // LDS slot of global slot s_g at row r: s_g ^ ((r>>1)&3), (r>>1)&3=(c31>>1)&3.
    const int c31 = lane & 31, h2 = lane >> 5;
    const int xr = (c31 >> 1) & 3;
    const int so0 = ((2 * h2) ^ xr) * 16;
    const int so1 = ((2 * h2 + 1) ^ xr) * 16;

    f32x16 acc[2] = {};
    const int sc = 0x7F7F7F7F;   // E8M0 127 -> scale 1.0 for any opsel

    // prologue: stage steps 0,1 (3 gloads/wave each); drain step 0, keep 1 flying
    STG_A(0, 0); STG_B(0, 0);
    STG_A(1, 1); STG_B(1, 1);
    VMCNT(3);
    BARRIER(); SCHED0();

#pragma unroll
    for (int s = 0; s < NSTEPS; ++s) {
        const int d = s % 3;
        if (s + 2 < NSTEPS) {
            const int dn = (s + 2) % 3;
            STG_A(dn, s + 2); STG_B(dn, s + 2);
        }
        i32x8 Af, Bf[2];
        {
            const int r = wm * 32 + c31;
            i32x4 lo = *(const i32x4*)&As[d][r * 64 + so0];
            i32x4 hi = *(const i32x4*)&As[d][r * 64 + so1];
            Af = (i32x8){lo[0], lo[1], lo[2], lo[3], hi[0], hi[1], hi[2], hi[3]};
        }
#pragma unroll
        for (int ni = 0; ni < 2; ++ni) {
            const int r = wn * 64 + ni * 32 + c31;
            i32x4 lo = *(const i32x4*)&Bs[d][r * 64 + so0];
            i32x4 hi = *(const i32x4*)&Bs[d][r * 64 + so1];
            Bf[ni] = (i32x8){lo[0], lo[1], lo[2], lo[3], hi[0], hi[1], hi[2], hi[3]};
        }
#pragma unroll
        for (int ni = 0; ni < 2; ++ni)
            acc[ni] = __builtin_amdgcn_mfma_scale_f32_32x32x64_f8f6f4(
                Af, Bf[ni], acc[ni], 0, 0, 0, sc, 0, sc);

        // boundary: certify step s+1 landed for all waves; keep s+2 flying
        if (s <= NSTEPS - 3)       { VMCNT(3); BARRIER(); SCHED0(); }
        else if (s == NSTEPS - 2)  { VMCNT(0); BARRIER(); SCHED0(); }
    }

    // ---- epilogue: exp + masked diag + row/col reduction ----
    // C/D 32x32 layout: col = lane&31, row = (reg&3) + 8*(reg>>2) + 4*(lane>>5)
    const float invT = 1.0f / temp[0];
    const bool diagBlk = ((bm >> 1) == bn);
    float colpart[2] = {0.f, 0.f};
    float rowpart[16];
#pragma unroll
    for (int r = 0; r < 16; ++r) rowpart[r] = 0.f;

#pragma unroll
    for (int ni = 0; ni < 2; ++ni) {
        f32x16 a = acc[ni];
#pragma unroll
        for (int r = 0; r < 16; ++r) {
            float e = __expf((a[r] - 1.0f) * invT);
            if (diagBlk) {
                int grow = bm * 64 + wm * 32 + (r & 3) + 8 * (r >> 2) + 4 * h2;
                int gcol = bn * 128 + wn * 64 + ni * 32 + c31;
                if (grow == gcol) e = 0.f;
            }
            rowpart[r] += e;
            colpart[ni] += e;
        }
    }
#pragma unroll
    for (int r = 0; r < 16; ++r) {
        float v = rowpart[r];
        v += __shfl_xor(v, 1);
        v += __shfl_xor(v, 2);
        v += __shfl_xor(v, 4);
        v += __shfl_xor(v, 8);
        v += __shfl_xor(v, 16);
        if (c31 == 0)
            atomicAdd(&rs_l[wm * 32 + (r & 3) + 8 * (r >> 2) + 4 * h2], v);
    }
#pragma unroll
    for (int ni = 0; ni < 2; ++ni) {
        float v = colpart[ni];
        v += __shfl_xor(v, 32);
        if (h2 == 0) atomicAdd(&cs_l[wn * 64 + ni * 32 + c31], v);
    }
    __syncthreads();
    if (tid < 64) atomicAdd(&row_sum[bm * 64 + tid], rs_l[tid]);
    else if (tid < 192) atomicAdd(&col_sum[bn * 128 + (tid - 64)], cs_l[tid - 64]);
}

// loss = mean_i [ 2M + log(rs_i) + log(cs_i) - 2*diag_i ],  M = 1/temp
__global__ void finalize_kernel(const float* __restrict__ rs, const float* __restrict__ cs,
                                const float* __restrict__ dg, const float* __restrict__ temp,
                                float* __restrict__ out) {
    const float M = 1.0f / temp[0];
    float acc = 0.f;
    for (int i = threadIdx.x; i < N_ROWS; i += 256)
        acc += 2.f * M + __logf(rs[i]) + __logf(cs[i]) - 2.f * dg[i];
#pragma unroll
    for (int s = 1; s < 64; s <<= 1) acc += __shfl_xor(acc, s);
    __shared__ float wsum[4];
    if ((threadIdx.x & 63) == 0) wsum[threadIdx.x >> 6] = acc;
    __syncthreads();
    if (threadIdx.x == 0)
        out[0] = (wsum[0] + wsum[1] + wsum[2] + wsum[3]) / (float)N_ROWS;
}

extern "C" void kernel_launch(void* const* d_in, const int* in_sizes, int n_in,
                              void* d_out, int out_size, void* d_ws, size_t ws_size,
                              hipStream_t stream) {
    const float* cxr = (const float*)d_in[0];
    const float* ehr = (const float*)d_in[1];
    const float* temp = (const float*)d_in[2];
    float* out = (float*)d_out;

    char* ws = (char*)d_ws;
    unsigned char* Ab = (unsigned char*)ws;                        // 4 MB
    unsigned char* Bb = (unsigned char*)(ws + 4u * 1024 * 1024);   // 4 MB
    float* rs = (float*)(ws + 8u * 1024 * 1024);
    float* cs = rs + N_ROWS;
    float* dg = cs + N_ROWS;

    hipMemsetAsync(rs, 0, 2 * N_ROWS * sizeof(float), stream);
    normdiag_kernel<<<dim3(N_ROWS / 4), 256, 0, stream>>>(cxr, ehr, Ab, Bb, temp, dg);
    gemm_lse_kernel<<<dim3(128 * 64), 256, 0, stream>>>(Ab, Bb, temp, rs, cs);
    finalize_kernel<<<1, 256, 0, stream>>>(rs, cs, dg, temp, out);
}